// Round 1
// baseline (84.620 us; speedup 1.0000x reference)
//
#include <hip/hip_runtime.h>
#include <math.h>

#define BB 4
#define CC 256
#define HW (128*128)
#define NC 19
#define NV 50
#define PP (NC*NV)          // 950
#define TR 8
#define INV_T (1.0f/0.07f)

// Gather: Xq row-major [b][p][c]; Xk transposed-packed [b][c/4][p][4]
__global__ __launch_bounds__(256)
void gather_kernel(const float* __restrict__ fq,
                   const float* __restrict__ fk,
                   const int* __restrict__ sidx,
                   float* __restrict__ xq_g,
                   float* __restrict__ xk_t) {
    int bp = blockIdx.x;              // 0 .. B*P-1
    int b = bp / PP;
    int p = bp - b * PP;
    int pix = sidx[bp];
    int c = threadIdx.x;              // 0..255
    size_t src = ((size_t)b * CC + c) * HW + pix;
    float vq = fq[src];
    float vk = fk[src];
    xq_g[((size_t)b * PP + p) * CC + c] = vq;
    xk_t[(((size_t)b * (CC/4) + (c >> 2)) * PP + p) * 4 + (c & 3)] = vk;
}

__global__ __launch_bounds__(256)
void nce_kernel(const float* __restrict__ xq_g,
                const float* __restrict__ xk_t,
                float* __restrict__ out) {
    __shared__ float xq_lds[TR][CC];
    __shared__ float pos_lds[TR];
    __shared__ float red_m[4][TR];
    __shared__ float red_s[4][TR];

    int b  = blockIdx.y;
    int r0 = blockIdx.x * TR;
    int tid = threadIdx.x;

    // stage 8 q-rows into LDS (coalesced float4)
    for (int i = tid; i < TR * (CC/4); i += 256) {
        int r  = i / (CC/4);
        int c4 = i - r * (CC/4);
        int row = r0 + r;
        float4 v = make_float4(0.f, 0.f, 0.f, 0.f);
        if (row < PP) v = *(const float4*)&xq_g[((size_t)b * PP + row) * CC + c4 * 4];
        *(float4*)&xq_lds[r][c4 * 4] = v;
    }
    __syncthreads();

    int wave = tid >> 6, lane = tid & 63;
    int cbase = wave * 64 + lane;
    int cols[4], colc[4];
#pragma unroll
    for (int j = 0; j < 4; ++j) {
        cols[j] = cbase + j * 256;
        colc[j] = cols[j] < PP ? cols[j] : PP - 1;   // clamp: compute junk, mask later
    }

    float acc[TR][4];
#pragma unroll
    for (int r = 0; r < TR; ++r)
#pragma unroll
        for (int j = 0; j < 4; ++j) acc[r][j] = 0.f;

    const float4* kt = (const float4*)xk_t;

    for (int c4 = 0; c4 < CC/4; ++c4) {
        float4 kv[4];
#pragma unroll
        for (int j = 0; j < 4; ++j)
            kv[j] = kt[((size_t)b * (CC/4) + c4) * PP + colc[j]];
#pragma unroll
        for (int r = 0; r < TR; ++r) {
            float4 qv = *(const float4*)&xq_lds[r][c4 * 4];
#pragma unroll
            for (int j = 0; j < 4; ++j) {
                acc[r][j] += qv.x * kv[j].x;
                acc[r][j] += qv.y * kv[j].y;
                acc[r][j] += qv.z * kv[j].z;
                acc[r][j] += qv.w * kv[j].w;
            }
        }
    }

    // masked online-LSE per row: local 4 cols -> 64-lane butterfly -> cross-wave
#pragma unroll
    for (int r = 0; r < TR; ++r) {
        int row = r0 + r;
        int rcls = row / NV;
        float m = -INFINITY, s = 0.f;
#pragma unroll
        for (int j = 0; j < 4; ++j) {
            int col = cols[j];
            float x = acc[r][j] * INV_T;
            bool in_row = (row < PP);
            bool ok = in_row && (col < PP) && ((col / NV != rcls) || (col == row));
            if (in_row && (col == row)) pos_lds[r] = x;   // unique owner
            if (ok) {
                if (x > m) { s = s * __expf(m - x) + 1.f; m = x; }
                else       { s += __expf(x - m); }
            }
        }
#pragma unroll
        for (int off = 32; off >= 1; off >>= 1) {
            float m2 = __shfl_xor(m, off, 64);
            float s2 = __shfl_xor(s, off, 64);
            float nm = fmaxf(m, m2);
            s = s * __expf(m - nm) + s2 * __expf(m2 - nm);
            m = nm;
        }
        if (lane == 0) { red_m[wave][r] = m; red_s[wave][r] = s; }
    }
    __syncthreads();

    if (tid < TR) {
        int row = r0 + tid;
        if (row < PP) {
            float m = red_m[0][tid], s = red_s[0][tid];
#pragma unroll
            for (int w = 1; w < 4; ++w) {
                float m2 = red_m[w][tid], s2 = red_s[w][tid];
                float nm = fmaxf(m, m2);
                s = s * __expf(m - nm) + s2 * __expf(m2 - nm);
                m = nm;
            }
            out[(size_t)b * PP + row] = m + logf(s) - pos_lds[tid];
        }
    }
}

extern "C" void kernel_launch(void* const* d_in, const int* in_sizes, int n_in,
                              void* d_out, int out_size, void* d_ws, size_t ws_size,
                              hipStream_t stream) {
    const float* fq   = (const float*)d_in[0];
    const float* fk   = (const float*)d_in[1];
    const int*   sidx = (const int*)d_in[2];
    float* outp = (float*)d_out;

    float* xq_g = (float*)d_ws;                           // B*P*C floats
    float* xk_t = xq_g + (size_t)BB * PP * CC;            // B*(C/4)*P*4 floats

    gather_kernel<<<dim3(BB * PP), 256, 0, stream>>>(fq, fk, sidx, xq_g, xk_t);
    nce_kernel<<<dim3((PP + TR - 1) / TR, BB), 256, 0, stream>>>(xq_g, xk_t, outp);
}

// Round 2
// 72.940 us; speedup vs baseline: 1.1601x; 1.1601x over previous
//
#include <hip/hip_runtime.h>
#include <math.h>

#define BB 4
#define CC 256
#define HW (128*128)
#define NC 19
#define NV 50
#define PP (NC*NV)          // 950
#define INV_T (1.0f/0.07f)
#define NELEM ((size_t)BB * PP * CC)

typedef short bf16x8 __attribute__((ext_vector_type(8)));
typedef float f32x4  __attribute__((ext_vector_type(4)));

static __device__ __forceinline__ unsigned short f2bf(float f) {
    unsigned int u = __float_as_uint(f);
    unsigned int r = (u + 0x7fffu + ((u >> 16) & 1u)) >> 16;   // RNE
    return (unsigned short)r;
}
static __device__ __forceinline__ float bf2f(unsigned short h) {
    return __uint_as_float(((unsigned int)h) << 16);
}

// Gather + split fp32 -> (hi, lo) bf16 planes, row-major [b][p][c]
__global__ __launch_bounds__(256)
void gather_kernel(const float* __restrict__ fq,
                   const float* __restrict__ fk,
                   const int* __restrict__ sidx,
                   unsigned short* __restrict__ xqh,
                   unsigned short* __restrict__ xql,
                   unsigned short* __restrict__ xkh,
                   unsigned short* __restrict__ xkl) {
    int bp = blockIdx.x;              // 0 .. B*P-1
    int b = bp / PP;
    int p = bp - b * PP;
    int pix = sidx[bp];
    int c = threadIdx.x;
    size_t src = ((size_t)b * CC + c) * HW + pix;
    float vq = fq[src];
    float vk = fk[src];
    size_t dst = ((size_t)b * PP + p) * CC + c;
    unsigned short qh = f2bf(vq);
    unsigned short kh = f2bf(vk);
    xqh[dst] = qh;
    xql[dst] = f2bf(vq - bf2f(qh));
    xkh[dst] = kh;
    xkl[dst] = f2bf(vk - bf2f(kh));
}

__device__ __forceinline__ void lse_merge(float& m, float& s, float m2, float s2) {
    float nm = fmaxf(m, m2);
    float d1 = m - nm;  d1 = (d1 < 0.f) ? d1 : 0.f;   // also kills NaN from inf-inf
    float d2 = m2 - nm; d2 = (d2 < 0.f) ? d2 : 0.f;
    s = s * __expf(d1) + s2 * __expf(d2);
    m = nm;
}

// One block per (b, 16-row tile). 8 waves; wave w handles column tiles w, w+8, ...
__global__ __launch_bounds__(512)
void nce_mfma(const unsigned short* __restrict__ xqh,
              const unsigned short* __restrict__ xql,
              const unsigned short* __restrict__ xkh,
              const unsigned short* __restrict__ xkl,
              float* __restrict__ out) {
    __shared__ float pos_lds[16];
    __shared__ float red_m[8][16];
    __shared__ float red_s[8][16];

    int b  = blockIdx.y;
    int r0 = blockIdx.x * 16;
    int tid = threadIdx.x;
    int w = tid >> 6, l = tid & 63;
    int lr = l & 15;          // fragment row/col index
    int lg = l >> 4;          // k-group

    // ---- A fragments (16 rows, K=256, hi+lo) held in registers ----
    int arow = r0 + lr; if (arow > PP - 1) arow = PP - 1;
    size_t abase = ((size_t)b * PP + arow) * CC + lg * 8;
    bf16x8 Ah[8], Al[8];
#pragma unroll
    for (int kt = 0; kt < 8; ++kt) {
        Ah[kt] = *(const bf16x8*)(xqh + abase + kt * 32);
        Al[kt] = *(const bf16x8*)(xql + abase + kt * 32);
    }

    // per-lane rows for the C fragment: row = r0 + lg*4 + j
    int   rcls[4];
    bool  rok[4];
    float m[4], s[4];
#pragma unroll
    for (int j = 0; j < 4; ++j) {
        int row = r0 + lg * 4 + j;
        rok[j]  = (row < PP);
        rcls[j] = row / NV;
        m[j] = -INFINITY;
        s[j] = 0.f;
    }

    for (int t = w; t < 60; t += 8) {
        int n0 = t * 16;
        int brow = n0 + lr; if (brow > PP - 1) brow = PP - 1;
        size_t bbase = ((size_t)b * PP + brow) * CC + lg * 8;
        bf16x8 Bh[8], Bl[8];
#pragma unroll
        for (int kt = 0; kt < 8; ++kt) {
            Bh[kt] = *(const bf16x8*)(xkh + bbase + kt * 32);
            Bl[kt] = *(const bf16x8*)(xkl + bbase + kt * 32);
        }
        f32x4 acc = {0.f, 0.f, 0.f, 0.f};
#pragma unroll
        for (int kt = 0; kt < 8; ++kt) {
            acc = __builtin_amdgcn_mfma_f32_16x16x32_bf16(Ah[kt], Bh[kt], acc, 0, 0, 0);
            acc = __builtin_amdgcn_mfma_f32_16x16x32_bf16(Ah[kt], Bl[kt], acc, 0, 0, 0);
            acc = __builtin_amdgcn_mfma_f32_16x16x32_bf16(Al[kt], Bh[kt], acc, 0, 0, 0);
        }

        int col = n0 + lr;
        bool colok = (col < PP);
        int ccls = col / NV;
#pragma unroll
        for (int j = 0; j < 4; ++j) {
            float x = acc[j] * INV_T;
            int row = r0 + lg * 4 + j;
            if (rok[j] && col == row) pos_lds[lg * 4 + j] = x;   // unique owner
            bool ok = rok[j] && colok && ((ccls != rcls[j]) || (col == row));
            if (ok) {
                if (x > m[j]) { s[j] = s[j] * __expf(m[j] - x) + 1.f; m[j] = x; }
                else          { s[j] += __expf(x - m[j]); }
            }
        }
    }

    // butterfly over the 16 column-lanes (low 4 lane bits)
#pragma unroll
    for (int j = 0; j < 4; ++j) {
#pragma unroll
        for (int off = 1; off <= 8; off <<= 1) {
            float m2 = __shfl_xor(m[j], off, 64);
            float s2 = __shfl_xor(s[j], off, 64);
            lse_merge(m[j], s[j], m2, s2);
        }
    }
    if (lr == 0) {
#pragma unroll
        for (int j = 0; j < 4; ++j) {
            red_m[w][lg * 4 + j] = m[j];
            red_s[w][lg * 4 + j] = s[j];
        }
    }
    __syncthreads();

    if (tid < 16) {
        int row = r0 + tid;
        if (row < PP) {
            float mm = red_m[0][tid], ss = red_s[0][tid];
#pragma unroll
            for (int ww = 1; ww < 8; ++ww)
                lse_merge(mm, ss, red_m[ww][tid], red_s[ww][tid]);
            out[(size_t)b * PP + row] = mm + logf(ss) - pos_lds[tid];
        }
    }
}

extern "C" void kernel_launch(void* const* d_in, const int* in_sizes, int n_in,
                              void* d_out, int out_size, void* d_ws, size_t ws_size,
                              hipStream_t stream) {
    const float* fq   = (const float*)d_in[0];
    const float* fk   = (const float*)d_in[1];
    const int*   sidx = (const int*)d_in[2];
    float* outp = (float*)d_out;

    unsigned short* base = (unsigned short*)d_ws;
    unsigned short* xqh = base;
    unsigned short* xql = base + NELEM;
    unsigned short* xkh = base + 2 * NELEM;
    unsigned short* xkl = base + 3 * NELEM;

    gather_kernel<<<dim3(BB * PP), 256, 0, stream>>>(fq, fk, sidx, xqh, xql, xkh, xkl);
    nce_mfma<<<dim3(60, BB), 512, 0, stream>>>(xqh, xql, xkh, xkl, outp);
}